// Round 1
// 584.094 us; speedup vs baseline: 1.1802x; 1.1802x over previous
//
#include <hip/hip_runtime.h>

// CBAM attention, fp32 in/out. B=32, C=512, Cr=64, H=W=64, HW=4096.
// Pipeline: [pool over HW] -> [spectral norms] -> [MLP -> s] ->
//           [x*s, pool over C -> ca/cm] -> [3x3 conv -> sy] -> [out = x*s*sy]
//
// R1: occupancy restructure. conv_out split into tiny conv_sy + grid-stride
// elementwise (32 waves/CU vs 1/SIMD before); scale_pool goes 1024-thread
// with 4-way C-split + LDS combine; sv_kernel parallelized over 3 blocks.

#define B_   32
#define C_   512
#define CR_  64
#define HW_  4096
#define WID_ 64
#define EPSF 1e-12f

__device__ __forceinline__ float sigmoidf(float x) {
  return 1.0f / (1.0f + __expf(-x));
}

// ---------------- K1: avg/max over HW per (b,c) plane ----------------
__global__ __launch_bounds__(256) void pool_kernel(const float* __restrict__ x,
                                                   float* __restrict__ avg,
                                                   float* __restrict__ mx) {
  const int plane = blockIdx.x;           // b*C + c: 4096 contiguous floats
  const int t = threadIdx.x;
  const float4* xp = (const float4*)(x + (size_t)plane * HW_);
  float s = 0.0f, m = -INFINITY;
  #pragma unroll
  for (int q = 0; q < 4; q++) {
    float4 a = xp[q * 256 + t];
    s += (a.x + a.y) + (a.z + a.w);
    m = fmaxf(m, fmaxf(fmaxf(a.x, a.y), fmaxf(a.z, a.w)));
  }
  for (int o = 32; o > 0; o >>= 1) {
    s += __shfl_down(s, o);
    m = fmaxf(m, __shfl_down(m, o));
  }
  __shared__ float rs[4], rm[4];
  int wave = t >> 6, lane = t & 63;
  if (lane == 0) { rs[wave] = s; rm[wave] = m; }
  __syncthreads();
  if (t == 0) {
    float S = rs[0] + rs[1] + rs[2] + rs[3];
    float M = fmaxf(fmaxf(rm[0], rm[1]), fmaxf(rm[2], rm[3]));
    avg[plane] = S * (1.0f / HW_);
    mx[plane] = M;
  }
}

// ---------------- K2: spectral norms, 3 blocks (one per sv) ----------------
__device__ __forceinline__ float block_reduce_sum(float v, float* red) {
  int t = threadIdx.x;
  red[t] = v;
  __syncthreads();
  for (int o = 128; o > 0; o >>= 1) {
    if (t < o) red[t] += red[t + o];
    __syncthreads();
  }
  float r = red[0];
  __syncthreads();
  return r;
}

__global__ __launch_bounds__(256) void sv_kernel(const float* __restrict__ w1, const float* __restrict__ u1,
                                                 const float* __restrict__ w2, const float* __restrict__ u2,
                                                 const float* __restrict__ w3, const float* __restrict__ u3,
                                                 float* __restrict__ sv) {
  __shared__ float v[C_];
  __shared__ float red[256];
  __shared__ float tmp[C_];
  const int t = threadIdx.x;
  const int blk = blockIdx.x;

  if (blk == 0) {
    // ---- sv1: W1m = [CR_=64, C_=512] ----
    if (t < CR_) tmp[t] = u1[t];
    __syncthreads();
    // v[j] = sum_i u1[i]*w1[i*512+j]; thread t -> j = 2t, 2t+1 (float2)
    float ax = 0.0f, ay = 0.0f;
    for (int i = 0; i < CR_; i++) {
      float ui = tmp[i];
      float2 wv = *(const float2*)(w1 + (size_t)i * C_ + 2 * t);
      ax += ui * wv.x; ay += ui * wv.y;
    }
    v[2 * t] = ax; v[2 * t + 1] = ay;
    float nv = block_reduce_sum(ax * ax + ay * ay, red);
    float dv = fmaxf(sqrtf(nv), EPSF);
    // a_i = sum_j v[j]*w1[i*512+j]; 4 lanes per output i
    int i = t >> 2, part = t & 3;
    const float4* wr = (const float4*)(w1 + (size_t)i * C_ + part * 128);
    float acc = 0.0f;
    #pragma unroll 8
    for (int q = 0; q < 32; q++) {
      float4 wv = wr[q];
      int j = part * 128 + 4 * q;
      acc += v[j] * wv.x + v[j + 1] * wv.y + v[j + 2] * wv.z + v[j + 3] * wv.w;
    }
    acc += __shfl_down(acc, 2);
    acc += __shfl_down(acc, 1);
    float q2 = 0.0f;
    if (part == 0) { float a2 = acc / dv; q2 = a2 * a2; }
    float nt2 = block_reduce_sum(q2, red);
    if (t == 0) sv[0] = nt2 / fmaxf(sqrtf(nt2), EPSF);

  } else if (blk == 1) {
    // ---- sv2: W2m = [C_=512, CR_=64] ----
    for (int i = t; i < C_; i += 256) tmp[i] = u2[i];
    __syncthreads();
    // v[j] = sum_i u2[i]*w2[i*64+j], j<64; 4 i-groups of 128
    int j = t & 63, ig = t >> 6;
    const float* wp = w2 + (size_t)ig * 128 * CR_ + j;
    float a = 0.0f;
    #pragma unroll 8
    for (int i = 0; i < 128; i++) a += tmp[ig * 128 + i] * wp[(size_t)i * CR_];
    red[t] = a;
    __syncthreads();
    if (t < CR_) v[t] = red[t] + red[t + 64] + red[t + 128] + red[t + 192];
    __syncthreads();
    float p = (t < CR_) ? v[t] * v[t] : 0.0f;
    float nv = block_reduce_sum(p, red);
    float dv = fmaxf(sqrtf(nv), EPSF);
    // a_i = sum_j v[j]*w2[i*64+j], i<512; thread t -> i = t, t+256
    float q = 0.0f;
    #pragma unroll
    for (int rep = 0; rep < 2; rep++) {
      int i = t + rep * 256;
      const float4* wr = (const float4*)(w2 + (size_t)i * CR_);
      float acc = 0.0f;
      #pragma unroll
      for (int qq = 0; qq < 16; qq++) {
        float4 wv = wr[qq];
        acc += v[4 * qq] * wv.x + v[4 * qq + 1] * wv.y +
               v[4 * qq + 2] * wv.z + v[4 * qq + 3] * wv.w;
      }
      acc /= dv;
      q += acc * acc;
    }
    float nt2 = block_reduce_sum(q, red);
    if (t == 0) sv[1] = nt2 / fmaxf(sqrtf(nt2), EPSF);

  } else {
    // ---- sv3: W3m = [1, 18] ----
    if (t == 0) {
      float u3v = u3[0];
      float nvs = 0.0f;
      for (int k = 0; k < 18; k++) { float vv = u3v * w3[k]; nvs += vv * vv; }
      float d = fmaxf(sqrtf(nvs), EPSF);
      float tt = 0.0f;
      for (int k = 0; k < 18; k++) tt += (u3v * w3[k] / d) * w3[k];
      float u2n = tt / fmaxf(fabsf(tt), EPSF);
      sv[2] = tt * u2n;
    }
  }
}

// ---------------- K3: MLP -> s[B,C] ----------------
__global__ __launch_bounds__(256) void mlp_kernel(const float* __restrict__ avg, const float* __restrict__ mx,
                                                  const float* __restrict__ w1, const float* __restrict__ b1,
                                                  const float* __restrict__ w2, const float* __restrict__ b2,
                                                  const float* __restrict__ sv, float* __restrict__ s) {
  const int b = blockIdx.x;
  const int t = threadIdx.x;
  __shared__ float pool[2][C_];
  __shared__ float hid[2][CR_];
  for (int i = t; i < C_; i += 256) {
    pool[0][i] = avg[b * C_ + i];
    pool[1][i] = mx[b * C_ + i];
  }
  __syncthreads();
  const float inv1 = 1.0f / sv[0];
  const float inv2 = 1.0f / sv[1];
  if (t < 2 * CR_) {
    int kind = t >> 6;      // 0 = avg, 1 = max
    int i = t & 63;
    const float4* wr = (const float4*)(w1 + (size_t)i * C_);
    float acc = 0.0f;
    for (int qq = 0; qq < C_ / 4; qq++) {
      float4 u = wr[qq];
      acc += pool[kind][qq * 4 + 0] * u.x + pool[kind][qq * 4 + 1] * u.y +
             pool[kind][qq * 4 + 2] * u.z + pool[kind][qq * 4 + 3] * u.w;
    }
    hid[kind][i] = fmaxf(acc * inv1 + b1[i], 0.0f);
  }
  __syncthreads();
  for (int c = t; c < C_; c += 256) {
    const float* wr = w2 + (size_t)c * CR_;
    float aa = 0.0f, mm = 0.0f;
    #pragma unroll 8
    for (int i = 0; i < CR_; i++) {
      float wv = wr[i];
      aa += hid[0][i] * wv;
      mm += hid[1][i] * wv;
    }
    float val = (aa + mm) * inv2 + 2.0f * b2[c];
    s[b * C_ + c] = sigmoidf(val);
  }
}

// ---------------- K4: x*s, mean/max over C -> ca, cm (4-way C-split) ----------------
__global__ __launch_bounds__(1024) void scale_pool_kernel(const float* __restrict__ x,
                                                          const float* __restrict__ s,
                                                          float* __restrict__ ca,
                                                          float* __restrict__ cm) {
  const int b = blockIdx.y;
  const int hw0 = blockIdx.x * 512;
  const int t = threadIdx.x;          // 0..1023
  const int pxid = t & 255;           // 256 pixel-slots, 2 px each
  const int cg = t >> 8;              // 4 channel groups of 128
  __shared__ float srow[C_];
  for (int i = t; i < C_; i += 1024) srow[i] = s[b * C_ + i];
  __syncthreads();
  const int px = hw0 + pxid * 2;
  const float* xb = x + (size_t)b * C_ * HW_ + px;
  float s0 = 0.f, s1 = 0.f, m0 = -INFINITY, m1 = -INFINITY;
  const int c0 = cg * 128;
  #pragma unroll 8
  for (int c = c0; c < c0 + 128; c++) {
    float2 u = *(const float2*)(xb + (size_t)c * HW_);
    float sc = srow[c];
    float v0 = u.x * sc, v1 = u.y * sc;
    s0 += v0; s1 += v1;
    m0 = fmaxf(m0, v0); m1 = fmaxf(m1, v1);
  }
  __shared__ float rs0[4][256], rs1[4][256], rm0[4][256], rm1[4][256]; // 16 KB
  rs0[cg][pxid] = s0; rs1[cg][pxid] = s1;
  rm0[cg][pxid] = m0; rm1[cg][pxid] = m1;
  __syncthreads();
  if (cg == 0) {
    float S0 = rs0[0][pxid] + rs0[1][pxid] + rs0[2][pxid] + rs0[3][pxid];
    float S1 = rs1[0][pxid] + rs1[1][pxid] + rs1[2][pxid] + rs1[3][pxid];
    float M0 = fmaxf(fmaxf(rm0[0][pxid], rm0[1][pxid]), fmaxf(rm0[2][pxid], rm0[3][pxid]));
    float M1 = fmaxf(fmaxf(rm1[0][pxid], rm1[1][pxid]), fmaxf(rm1[2][pxid], rm1[3][pxid]));
    *(float2*)(ca + (size_t)b * HW_ + px) = make_float2(S0 * (1.0f / C_), S1 * (1.0f / C_));
    *(float2*)(cm + (size_t)b * HW_ + px) = make_float2(M0, M1);
  }
}

// ---------------- K5: 3x3 conv -> sy[B,HW] = sigmoid(y) ----------------
__global__ __launch_bounds__(256) void conv_sy_kernel(const float* __restrict__ ca,
                                                      const float* __restrict__ cm,
                                                      const float* __restrict__ w3,
                                                      const float* __restrict__ b3,
                                                      const float* __restrict__ sv,
                                                      float* __restrict__ sy) {
  const int b = blockIdx.y;
  const int hw0 = blockIdx.x * 512;
  const int t = threadIdx.x;
  const float inv3 = 1.0f / sv[2];
  float wn[18];
  #pragma unroll
  for (int k = 0; k < 18; k++) wn[k] = w3[k] * inv3;
  const float b3f = b3[0];

  #pragma unroll
  for (int e = 0; e < 2; e++) {
    int px = hw0 + t * 2 + e;
    int h = px >> 6, w = px & 63;
    float acc = b3f;
    #pragma unroll
    for (int dh = -1; dh <= 1; dh++) {
      int hh = h + dh;
      if (hh < 0 || hh >= 64) continue;
      #pragma unroll
      for (int dw = -1; dw <= 1; dw++) {
        int ww = w + dw;
        if (ww < 0 || ww >= WID_) continue;
        int n = b * HW_ + hh * WID_ + ww;
        int k = (dh + 1) * 3 + (dw + 1);
        acc += ca[n] * wn[k] + cm[n] * wn[9 + k];
      }
    }
    sy[b * HW_ + px] = sigmoidf(acc);
  }
}

// ---------------- K6: out = x * s[b,c] * sy[b,hw], grid-stride float4 ----------------
__global__ __launch_bounds__(256) void out_kernel(const float* __restrict__ x,
                                                  const float* __restrict__ s,
                                                  const float* __restrict__ sy,
                                                  float* __restrict__ out) {
  const size_t N4 = (size_t)B_ * C_ * HW_ / 4;   // 16,777,216 float4s
  const size_t stride = (size_t)gridDim.x * blockDim.x;
  for (size_t i = (size_t)blockIdx.x * blockDim.x + threadIdx.x; i < N4; i += stride) {
    size_t base = i * 4;
    int hw = (int)(base & (HW_ - 1));
    int bc = (int)(base >> 12);          // b*C + c
    int b  = bc >> 9;
    float sc = s[bc];
    float4 u = ((const float4*)x)[i];
    float4 g = *(const float4*)(sy + (size_t)b * HW_ + hw);
    float4 r;
    r.x = u.x * sc * g.x;
    r.y = u.y * sc * g.y;
    r.z = u.z * sc * g.z;
    r.w = u.w * sc * g.w;
    ((float4*)out)[i] = r;
  }
}

extern "C" void kernel_launch(void* const* d_in, const int* in_sizes, int n_in,
                              void* d_out, int out_size, void* d_ws, size_t ws_size,
                              hipStream_t stream) {
  const float* x  = (const float*)d_in[0];
  const float* w1 = (const float*)d_in[1];
  const float* b1 = (const float*)d_in[2];
  const float* u1 = (const float*)d_in[3];
  const float* w2 = (const float*)d_in[4];
  const float* b2 = (const float*)d_in[5];
  const float* u2 = (const float*)d_in[6];
  const float* w3 = (const float*)d_in[7];
  const float* b3 = (const float*)d_in[8];
  const float* u3 = (const float*)d_in[9];

  float* ws = (float*)d_ws;
  float* avg = ws;                    // 16384 floats
  float* mx  = ws + 16384;            // 16384
  float* s   = ws + 32768;            // 16384
  float* sv  = ws + 49152;            // 4 (padded to 16384)
  float* ca  = ws + 65536;            // 131072
  float* cm  = ws + 196608;           // 131072
  float* sy  = ws + 327680;           // 131072  (total 1.75 MiB)

  pool_kernel<<<B_ * C_, 256, 0, stream>>>(x, avg, mx);
  sv_kernel<<<3, 256, 0, stream>>>(w1, u1, w2, u2, w3, u3, sv);
  mlp_kernel<<<B_, 256, 0, stream>>>(avg, mx, w1, b1, w2, b2, sv, s);
  scale_pool_kernel<<<dim3(8, B_), 1024, 0, stream>>>(x, s, ca, cm);
  conv_sy_kernel<<<dim3(8, B_), 256, 0, stream>>>(ca, cm, w3, b3, sv, sy);
  out_kernel<<<2048, 256, 0, stream>>>(x, s, sy, (float*)d_out);
}

// Round 2
// 583.710 us; speedup vs baseline: 1.1810x; 1.0007x over previous
//
#include <hip/hip_runtime.h>

// CBAM attention, fp32 in/out. B=32, C=512, Cr=64, H=W=64, HW=4096.
// R2: kill sv_kernel (sv1/sv2 folded into mlp per-block, sv3 into conv_sy);
// pool -> wave-per-plane (no block reduce); scale_pool -> float4 + 8-way
// C-split + 1024 blocks; mlp -> 128 blocks with unrolled dots.

#define B_   32
#define C_   512
#define CR_  64
#define HW_  4096
#define WID_ 64
#define EPSF 1e-12f

__device__ __forceinline__ float sigmoidf(float x) {
  return 1.0f / (1.0f + __expf(-x));
}

// ---------------- K1: avg/max over HW, one wave per (b,c) plane ----------------
__global__ __launch_bounds__(256) void pool_kernel(const float* __restrict__ x,
                                                   float* __restrict__ avg,
                                                   float* __restrict__ mx) {
  const int plane = blockIdx.x * 4 + (threadIdx.x >> 6);  // 4 waves = 4 planes
  const int lane = threadIdx.x & 63;
  const float4* xp = (const float4*)(x + (size_t)plane * HW_);
  float s = 0.0f, m = -INFINITY;
  #pragma unroll
  for (int q = 0; q < 16; q++) {
    float4 a = xp[q * 64 + lane];
    s += (a.x + a.y) + (a.z + a.w);
    m = fmaxf(m, fmaxf(fmaxf(a.x, a.y), fmaxf(a.z, a.w)));
  }
  #pragma unroll
  for (int o = 32; o > 0; o >>= 1) {
    s += __shfl_down(s, o);
    m = fmaxf(m, __shfl_down(m, o));
  }
  if (lane == 0) {
    avg[plane] = s * (1.0f / HW_);
    mx[plane] = m;
  }
}

// ---------------- block reduce helper ----------------
__device__ __forceinline__ float block_reduce_sum(float v, float* red) {
  int t = threadIdx.x;
  red[t] = v;
  __syncthreads();
  for (int o = 128; o > 0; o >>= 1) {
    if (t < o) red[t] += red[t + o];
    __syncthreads();
  }
  float r = red[0];
  __syncthreads();
  return r;
}

// ---------------- K2: sv1+sv2 (redundant per block) + MLP -> s[B,C] ----------------
// grid: dim3(4, B_): blockIdx.x = output quarter, blockIdx.y = b
__global__ __launch_bounds__(256) void mlp_kernel(const float* __restrict__ avg, const float* __restrict__ mx,
                                                  const float* __restrict__ w1, const float* __restrict__ b1,
                                                  const float* __restrict__ u1,
                                                  const float* __restrict__ w2, const float* __restrict__ b2,
                                                  const float* __restrict__ u2,
                                                  float* __restrict__ s) {
  const int b = blockIdx.y;
  const int qtr = blockIdx.x;
  const int t = threadIdx.x;
  __shared__ float v[C_];
  __shared__ float red[256];
  __shared__ float pool2[2][C_];
  __shared__ float hid[2][CR_];

  // ---- sv1: W1m = [64, 512] ----
  if (t < CR_) hid[0][t] = u1[t];          // u1 temp
  __syncthreads();
  float ax = 0.0f, ay = 0.0f;
  #pragma unroll 8
  for (int i = 0; i < CR_; i++) {
    float ui = hid[0][i];
    float2 wv = *(const float2*)(w1 + (size_t)i * C_ + 2 * t);
    ax += ui * wv.x; ay += ui * wv.y;
  }
  v[2 * t] = ax; v[2 * t + 1] = ay;
  float nv = block_reduce_sum(ax * ax + ay * ay, red);
  float dv = fmaxf(sqrtf(nv), EPSF);
  {
    int i = t >> 2, part = t & 3;
    const float4* wr = (const float4*)(w1 + (size_t)i * C_ + part * 128);
    float acc = 0.0f;
    #pragma unroll 8
    for (int q = 0; q < 32; q++) {
      float4 wv = wr[q];
      int j = part * 128 + 4 * q;
      acc += v[j] * wv.x + v[j + 1] * wv.y + v[j + 2] * wv.z + v[j + 3] * wv.w;
    }
    acc += __shfl_down(acc, 2);
    acc += __shfl_down(acc, 1);
    float q2 = 0.0f;
    if (part == 0) { float a2 = acc / dv; q2 = a2 * a2; }
    nv = block_reduce_sum(q2, red);
  }
  const float inv1 = fmaxf(sqrtf(nv), EPSF) / nv;   // 1/sv1

  // ---- sv2: W2m = [512, 64] ----
  for (int i = t; i < C_; i += 256) pool2[0][i] = u2[i];  // u2 temp
  __syncthreads();
  {
    int j = t & 63, ig = t >> 6;
    const float* wp = w2 + (size_t)ig * 128 * CR_ + j;
    float a = 0.0f;
    #pragma unroll 8
    for (int i = 0; i < 128; i++) a += pool2[0][ig * 128 + i] * wp[(size_t)i * CR_];
    red[t] = a;
  }
  __syncthreads();
  if (t < CR_) v[t] = red[t] + red[t + 64] + red[t + 128] + red[t + 192];
  __syncthreads();
  float p = (t < CR_) ? v[t] * v[t] : 0.0f;
  nv = block_reduce_sum(p, red);
  dv = fmaxf(sqrtf(nv), EPSF);
  {
    float q = 0.0f;
    #pragma unroll
    for (int rep = 0; rep < 2; rep++) {
      int i = t + rep * 256;
      const float4* wr = (const float4*)(w2 + (size_t)i * CR_);
      float acc = 0.0f;
      #pragma unroll
      for (int qq = 0; qq < 16; qq++) {
        float4 wv = wr[qq];
        acc += v[4 * qq] * wv.x + v[4 * qq + 1] * wv.y +
               v[4 * qq + 2] * wv.z + v[4 * qq + 3] * wv.w;
      }
      acc /= dv;
      q += acc * acc;
    }
    nv = block_reduce_sum(q, red);
  }
  const float inv2 = fmaxf(sqrtf(nv), EPSF) / nv;   // 1/sv2

  // ---- MLP ----
  for (int i = t; i < C_; i += 256) {
    pool2[0][i] = avg[b * C_ + i];
    pool2[1][i] = mx[b * C_ + i];
  }
  __syncthreads();
  if (t < 2 * CR_) {
    int kind = t >> 6;      // 0 = avg, 1 = max
    int i = t & 63;
    const float4* wr = (const float4*)(w1 + (size_t)i * C_);
    float acc = 0.0f;
    #pragma unroll 8
    for (int qq = 0; qq < C_ / 4; qq++) {
      float4 u = wr[qq];
      acc += pool2[kind][qq * 4 + 0] * u.x + pool2[kind][qq * 4 + 1] * u.y +
             pool2[kind][qq * 4 + 2] * u.z + pool2[kind][qq * 4 + 3] * u.w;
    }
    hid[kind][i] = fmaxf(acc * inv1 + b1[i], 0.0f);
  }
  __syncthreads();
  if (t < 128) {
    int c = qtr * 128 + t;
    const float4* wr = (const float4*)(w2 + (size_t)c * CR_);
    float aa = 0.0f, mm = 0.0f;
    #pragma unroll
    for (int k = 0; k < 16; k++) {
      float4 wv = wr[k];
      aa += hid[0][4 * k] * wv.x + hid[0][4 * k + 1] * wv.y +
            hid[0][4 * k + 2] * wv.z + hid[0][4 * k + 3] * wv.w;
      mm += hid[1][4 * k] * wv.x + hid[1][4 * k + 1] * wv.y +
            hid[1][4 * k + 2] * wv.z + hid[1][4 * k + 3] * wv.w;
    }
    float val = (aa + mm) * inv2 + 2.0f * b2[c];
    s[b * C_ + c] = sigmoidf(val);
  }
}

// ---------------- K3: x*s, mean/max over C -> ca, cm ----------------
// grid dim3(32, B_), 256 thr: thread = (cg of 8)*(32 px-slots); 4 px float4/thread
__global__ __launch_bounds__(256) void scale_pool_kernel(const float* __restrict__ x,
                                                         const float* __restrict__ s,
                                                         float* __restrict__ ca,
                                                         float* __restrict__ cm) {
  const int b = blockIdx.y;
  const int hw0 = blockIdx.x * 128;
  const int t = threadIdx.x;
  const int pxs = t & 31;             // 32 slots * 4 px = 128 px
  const int cg = t >> 5;              // 8 groups * 64 channels
  __shared__ float srow[C_];
  for (int i = t; i < C_; i += 256) srow[i] = s[b * C_ + i];
  __syncthreads();
  const int px = hw0 + pxs * 4;
  const float* xb = x + (size_t)b * C_ * HW_ + px;
  float4 sm = make_float4(0.f, 0.f, 0.f, 0.f);
  float4 mxv = make_float4(-INFINITY, -INFINITY, -INFINITY, -INFINITY);
  const int c0 = cg * 64;
  #pragma unroll 8
  for (int c = c0; c < c0 + 64; c++) {
    float4 u = *(const float4*)(xb + (size_t)c * HW_);
    float sc = srow[c];
    float v0 = u.x * sc, v1 = u.y * sc, v2 = u.z * sc, v3 = u.w * sc;
    sm.x += v0; sm.y += v1; sm.z += v2; sm.w += v3;
    mxv.x = fmaxf(mxv.x, v0); mxv.y = fmaxf(mxv.y, v1);
    mxv.z = fmaxf(mxv.z, v2); mxv.w = fmaxf(mxv.w, v3);
  }
  __shared__ float4 rs[8][32], rm[8][32];  // 16 KB
  rs[cg][pxs] = sm; rm[cg][pxs] = mxv;
  __syncthreads();
  if (t < 32) {
    float4 S = rs[0][t], M = rm[0][t];
    #pragma unroll
    for (int g = 1; g < 8; g++) {
      float4 a = rs[g][t], m2 = rm[g][t];
      S.x += a.x; S.y += a.y; S.z += a.z; S.w += a.w;
      M.x = fmaxf(M.x, m2.x); M.y = fmaxf(M.y, m2.y);
      M.z = fmaxf(M.z, m2.z); M.w = fmaxf(M.w, m2.w);
    }
    S.x *= (1.0f / C_); S.y *= (1.0f / C_); S.z *= (1.0f / C_); S.w *= (1.0f / C_);
    *(float4*)(ca + (size_t)b * HW_ + hw0 + t * 4) = S;
    *(float4*)(cm + (size_t)b * HW_ + hw0 + t * 4) = M;
  }
}

// ---------------- K4: 3x3 conv -> sy = sigmoid(y)  (sv3 inline) ----------------
__global__ __launch_bounds__(256) void conv_sy_kernel(const float* __restrict__ ca,
                                                      const float* __restrict__ cm,
                                                      const float* __restrict__ w3,
                                                      const float* __restrict__ b3,
                                                      const float* __restrict__ u3,
                                                      float* __restrict__ sy) {
  const int b = blockIdx.y;
  const int hw0 = blockIdx.x * 512;
  const int t = threadIdx.x;
  __shared__ float ssv3;
  if (t == 0) {
    float u3v = u3[0];
    float nvs = 0.0f;
    for (int k = 0; k < 18; k++) { float vv = u3v * w3[k]; nvs += vv * vv; }
    float d = fmaxf(sqrtf(nvs), EPSF);
    float tt = 0.0f;
    for (int k = 0; k < 18; k++) tt += (u3v * w3[k] / d) * w3[k];
    float u2n = tt / fmaxf(fabsf(tt), EPSF);
    ssv3 = tt * u2n;
  }
  __syncthreads();
  const float inv3 = 1.0f / ssv3;
  float wn[18];
  #pragma unroll
  for (int k = 0; k < 18; k++) wn[k] = w3[k] * inv3;
  const float b3f = b3[0];

  #pragma unroll
  for (int e = 0; e < 2; e++) {
    int px = hw0 + t * 2 + e;
    int h = px >> 6, w = px & 63;
    float acc = b3f;
    #pragma unroll
    for (int dh = -1; dh <= 1; dh++) {
      int hh = h + dh;
      if (hh < 0 || hh >= 64) continue;
      #pragma unroll
      for (int dw = -1; dw <= 1; dw++) {
        int ww = w + dw;
        if (ww < 0 || ww >= WID_) continue;
        int n = b * HW_ + hh * WID_ + ww;
        int k = (dh + 1) * 3 + (dw + 1);
        acc += ca[n] * wn[k] + cm[n] * wn[9 + k];
      }
    }
    sy[b * HW_ + px] = sigmoidf(acc);
  }
}

// ---------------- K5: out = x * s[b,c] * sy[b,hw], grid-stride float4 ----------------
__global__ __launch_bounds__(256) void out_kernel(const float* __restrict__ x,
                                                  const float* __restrict__ s,
                                                  const float* __restrict__ sy,
                                                  float* __restrict__ out) {
  const size_t N4 = (size_t)B_ * C_ * HW_ / 4;   // 16,777,216 float4s
  const size_t stride = (size_t)gridDim.x * blockDim.x;
  for (size_t i = (size_t)blockIdx.x * blockDim.x + threadIdx.x; i < N4; i += stride) {
    size_t base = i * 4;
    int hw = (int)(base & (HW_ - 1));
    int bc = (int)(base >> 12);          // b*C + c
    int b  = bc >> 9;
    float sc = s[bc];
    float4 u = ((const float4*)x)[i];
    float4 g = *(const float4*)(sy + (size_t)b * HW_ + hw);
    float4 r;
    r.x = u.x * sc * g.x;
    r.y = u.y * sc * g.y;
    r.z = u.z * sc * g.z;
    r.w = u.w * sc * g.w;
    ((float4*)out)[i] = r;
  }
}

extern "C" void kernel_launch(void* const* d_in, const int* in_sizes, int n_in,
                              void* d_out, int out_size, void* d_ws, size_t ws_size,
                              hipStream_t stream) {
  const float* x  = (const float*)d_in[0];
  const float* w1 = (const float*)d_in[1];
  const float* b1 = (const float*)d_in[2];
  const float* u1 = (const float*)d_in[3];
  const float* w2 = (const float*)d_in[4];
  const float* b2 = (const float*)d_in[5];
  const float* u2 = (const float*)d_in[6];
  const float* w3 = (const float*)d_in[7];
  const float* b3 = (const float*)d_in[8];
  const float* u3 = (const float*)d_in[9];

  float* ws = (float*)d_ws;
  float* avg = ws;                    // 16384 floats
  float* mx  = ws + 16384;            // 16384
  float* s   = ws + 32768;            // 16384
  float* ca  = ws + 49152;            // 131072
  float* cm  = ws + 180224;           // 131072
  float* sy  = ws + 311296;           // 131072  (total ~1.7 MiB)

  pool_kernel<<<B_ * C_ / 4, 256, 0, stream>>>(x, avg, mx);
  mlp_kernel<<<dim3(4, B_), 256, 0, stream>>>(avg, mx, w1, b1, u1, w2, b2, u2, s);
  scale_pool_kernel<<<dim3(32, B_), 256, 0, stream>>>(x, s, ca, cm);
  conv_sy_kernel<<<dim3(8, B_), 256, 0, stream>>>(ca, cm, w3, b3, u3, sy);
  out_kernel<<<2048, 256, 0, stream>>>(x, s, sy, (float*)d_out);
}

// Round 3
// 562.531 us; speedup vs baseline: 1.2255x; 1.0376x over previous
//
#include <hip/hip_runtime.h>

// CBAM attention, fp32 in/out. B=32, C=512, Cr=64, H=W=64, HW=4096.
// R3: conv fused into out kernel (4 launches total); out pass uses
// nontemporal load/store to preserve x in LLC; mlp runs sv1/sv2 chains
// concurrently in two wave-groups.

#define B_   32
#define C_   512
#define CR_  64
#define HW_  4096
#define WID_ 64
#define EPSF 1e-12f

typedef float f32x4 __attribute__((ext_vector_type(4)));

__device__ __forceinline__ float sigmoidf(float x) {
  return 1.0f / (1.0f + __expf(-x));
}

// ---------------- K1: avg/max over HW, one wave per (b,c) plane ----------------
__global__ __launch_bounds__(256) void pool_kernel(const float* __restrict__ x,
                                                   float* __restrict__ avg,
                                                   float* __restrict__ mx) {
  const int plane = blockIdx.x * 4 + (threadIdx.x >> 6);  // 4 waves = 4 planes
  const int lane = threadIdx.x & 63;
  const float4* xp = (const float4*)(x + (size_t)plane * HW_);
  float s = 0.0f, m = -INFINITY;
  #pragma unroll
  for (int q = 0; q < 16; q++) {
    float4 a = xp[q * 64 + lane];
    s += (a.x + a.y) + (a.z + a.w);
    m = fmaxf(m, fmaxf(fmaxf(a.x, a.y), fmaxf(a.z, a.w)));
  }
  #pragma unroll
  for (int o = 32; o > 0; o >>= 1) {
    s += __shfl_down(s, o);
    m = fmaxf(m, __shfl_down(m, o));
  }
  if (lane == 0) {
    avg[plane] = s * (1.0f / HW_);
    mx[plane] = m;
  }
}

// ---------------- K2: sv1 || sv2 (wave-group parallel) + MLP -> s[B,C] ----------------
// grid: dim3(4, B_): blockIdx.x = output quarter, blockIdx.y = b
__global__ __launch_bounds__(256) void mlp_kernel(const float* __restrict__ avg, const float* __restrict__ mx,
                                                  const float* __restrict__ w1, const float* __restrict__ b1,
                                                  const float* __restrict__ u1,
                                                  const float* __restrict__ w2, const float* __restrict__ b2,
                                                  const float* __restrict__ u2,
                                                  float* __restrict__ s) {
  const int b = blockIdx.y;
  const int qtr = blockIdx.x;
  const int t = threadIdx.x;
  __shared__ float v1[C_];
  __shared__ float v2[CR_];
  __shared__ float red[256];
  __shared__ float part2[128];
  __shared__ float u1s[CR_];
  __shared__ float u2s[C_];
  __shared__ float pool2[2][C_];
  __shared__ float hid[2][CR_];

  // phase 0: stage all small vectors
  if (t < CR_) u1s[t] = u1[t];
  for (int i = t; i < C_; i += 256) {
    u2s[i] = u2[i];
    pool2[0][i] = avg[b * C_ + i];
    pool2[1][i] = mx[b * C_ + i];
  }
  __syncthreads();

  // phase A: g0 (t<128) computes v1 = u1 @ W1m; g1 computes v2 = u2 @ W2m partials
  float sqp = 0.0f;
  if (t < 128) {
    const int j0 = t * 4;
    float a0 = 0.f, a1 = 0.f, a2 = 0.f, a3 = 0.f;
    #pragma unroll 8
    for (int i = 0; i < CR_; i++) {
      float ui = u1s[i];
      float4 wv = *(const float4*)(w1 + (size_t)i * C_ + j0);
      a0 += ui * wv.x; a1 += ui * wv.y; a2 += ui * wv.z; a3 += ui * wv.w;
    }
    v1[j0] = a0; v1[j0 + 1] = a1; v1[j0 + 2] = a2; v1[j0 + 3] = a3;
    sqp = a0 * a0 + a1 * a1 + a2 * a2 + a3 * a3;
  } else {
    const int tt = t - 128, j = tt & 63, half = tt >> 6;
    const float* wp = w2 + (size_t)(half * 256) * CR_ + j;
    float a = 0.0f;
    #pragma unroll 8
    for (int i = 0; i < 256; i++) a += u2s[half * 256 + i] * wp[(size_t)i * CR_];
    part2[tt] = a;
  }
  __syncthreads();
  if (t >= 128) {
    const int tt = t - 128;
    if (tt < CR_) { float vv = part2[tt] + part2[tt + 64]; v2[tt] = vv; sqp = vv * vv; }
  }
  red[t] = sqp;
  __syncthreads();
  const int rbase = t & 128, ridx = t & 127;
  #pragma unroll
  for (int o = 64; o > 0; o >>= 1) {
    if (ridx < o) red[rbase + ridx] += red[rbase + ridx + o];
    __syncthreads();
  }
  const float dv1 = fmaxf(sqrtf(red[0]), EPSF);
  const float dv2 = fmaxf(sqrtf(red[128]), EPSF);
  __syncthreads();

  // phase C: g0: a1_i = (v1/dv1) @ W1m.T (64 outs, 2 thr each);
  //          g1: a2_i = (v2/dv2) @ W2m.T (512 outs, 4 per thr)
  float sq2 = 0.0f;
  if (t < 128) {
    const int i = t >> 1, part = t & 1;
    const float4* wr = (const float4*)(w1 + (size_t)i * C_ + part * 256);
    float acc = 0.0f;
    #pragma unroll 8
    for (int q = 0; q < 64; q++) {
      float4 wv = wr[q];
      int j = part * 256 + 4 * q;
      acc += v1[j] * wv.x + v1[j + 1] * wv.y + v1[j + 2] * wv.z + v1[j + 3] * wv.w;
    }
    acc += __shfl_down(acc, 1);
    if (part == 0) { float a2 = acc / dv1; sq2 = a2 * a2; }
  } else {
    const int tt = t - 128;
    #pragma unroll
    for (int r = 0; r < 4; r++) {
      const int i = tt * 4 + r;
      const float4* wr = (const float4*)(w2 + (size_t)i * CR_);
      float acc = 0.0f;
      #pragma unroll
      for (int q = 0; q < 16; q++) {
        float4 wv = wr[q];
        acc += v2[4 * q] * wv.x + v2[4 * q + 1] * wv.y +
               v2[4 * q + 2] * wv.z + v2[4 * q + 3] * wv.w;
      }
      acc /= dv2;
      sq2 += acc * acc;
    }
  }
  red[t] = sq2;
  __syncthreads();
  #pragma unroll
  for (int o = 64; o > 0; o >>= 1) {
    if (ridx < o) red[rbase + ridx] += red[rbase + ridx + o];
    __syncthreads();
  }
  const float nt1 = red[0], nt2 = red[128];
  const float inv1 = fmaxf(sqrtf(nt1), EPSF) / nt1;   // 1/sv1
  const float inv2 = fmaxf(sqrtf(nt2), EPSF) / nt2;   // 1/sv2
  __syncthreads();

  // phase E: MLP
  if (t < 2 * CR_) {
    const int kind = t >> 6, i = t & 63;
    const float4* wr = (const float4*)(w1 + (size_t)i * C_);
    float acc = 0.0f;
    #pragma unroll 8
    for (int qq = 0; qq < C_ / 4; qq++) {
      float4 u = wr[qq];
      acc += pool2[kind][qq * 4 + 0] * u.x + pool2[kind][qq * 4 + 1] * u.y +
             pool2[kind][qq * 4 + 2] * u.z + pool2[kind][qq * 4 + 3] * u.w;
    }
    hid[kind][i] = fmaxf(acc * inv1 + b1[i], 0.0f);
  }
  __syncthreads();
  if (t < 128) {
    const int c = qtr * 128 + t;
    const float4* wr = (const float4*)(w2 + (size_t)c * CR_);
    float aa = 0.0f, mm = 0.0f;
    #pragma unroll
    for (int k = 0; k < 16; k++) {
      float4 wv = wr[k];
      aa += hid[0][4 * k] * wv.x + hid[0][4 * k + 1] * wv.y +
            hid[0][4 * k + 2] * wv.z + hid[0][4 * k + 3] * wv.w;
      mm += hid[1][4 * k] * wv.x + hid[1][4 * k + 1] * wv.y +
            hid[1][4 * k + 2] * wv.z + hid[1][4 * k + 3] * wv.w;
    }
    float val = (aa + mm) * inv2 + 2.0f * b2[c];
    s[b * C_ + c] = sigmoidf(val);
  }
}

// ---------------- K3: x*s, mean/max over C -> ca, cm ----------------
// grid dim3(32, B_), 256 thr: 8 c-groups x 32 px-slots; 4 px float4/thread
__global__ __launch_bounds__(256) void scale_pool_kernel(const float* __restrict__ x,
                                                         const float* __restrict__ s,
                                                         float* __restrict__ ca,
                                                         float* __restrict__ cm) {
  const int b = blockIdx.y;
  const int hw0 = blockIdx.x * 128;
  const int t = threadIdx.x;
  const int pxs = t & 31;             // 32 slots * 4 px = 128 px
  const int cg = t >> 5;              // 8 groups * 64 channels
  __shared__ float srow[C_];
  for (int i = t; i < C_; i += 256) srow[i] = s[b * C_ + i];
  __syncthreads();
  const int px = hw0 + pxs * 4;
  const float* xb = x + (size_t)b * C_ * HW_ + px;
  float4 sm = make_float4(0.f, 0.f, 0.f, 0.f);
  float4 mxv = make_float4(-INFINITY, -INFINITY, -INFINITY, -INFINITY);
  const int c0 = cg * 64;
  #pragma unroll 8
  for (int c = c0; c < c0 + 64; c++) {
    float4 u = *(const float4*)(xb + (size_t)c * HW_);
    float sc = srow[c];
    float v0 = u.x * sc, v1 = u.y * sc, v2 = u.z * sc, v3 = u.w * sc;
    sm.x += v0; sm.y += v1; sm.z += v2; sm.w += v3;
    mxv.x = fmaxf(mxv.x, v0); mxv.y = fmaxf(mxv.y, v1);
    mxv.z = fmaxf(mxv.z, v2); mxv.w = fmaxf(mxv.w, v3);
  }
  __shared__ float4 rs[8][32], rm[8][32];  // 16 KB
  rs[cg][pxs] = sm; rm[cg][pxs] = mxv;
  __syncthreads();
  if (t < 32) {
    float4 S = rs[0][t], M = rm[0][t];
    #pragma unroll
    for (int g = 1; g < 8; g++) {
      float4 a = rs[g][t], m2 = rm[g][t];
      S.x += a.x; S.y += a.y; S.z += a.z; S.w += a.w;
      M.x = fmaxf(M.x, m2.x); M.y = fmaxf(M.y, m2.y);
      M.z = fmaxf(M.z, m2.z); M.w = fmaxf(M.w, m2.w);
    }
    S.x *= (1.0f / C_); S.y *= (1.0f / C_); S.z *= (1.0f / C_); S.w *= (1.0f / C_);
    *(float4*)(ca + (size_t)b * HW_ + hw0 + t * 4) = S;
    *(float4*)(cm + (size_t)b * HW_ + hw0 + t * 4) = M;
  }
}

// ---------------- K4: conv(3x3, sv3) -> sy in LDS; out = x*s*sy (NT stream) ----------------
// grid dim3(32, B_), 256 thr; block owns 128 px x all 512 channels
__global__ __launch_bounds__(256) void conv_out_kernel(const float* __restrict__ x,
                                                       const float* __restrict__ s,
                                                       const float* __restrict__ ca,
                                                       const float* __restrict__ cm,
                                                       const float* __restrict__ w3,
                                                       const float* __restrict__ b3,
                                                       const float* __restrict__ u3,
                                                       float* __restrict__ out) {
  const int b = blockIdx.y;
  const int hw0 = blockIdx.x * 128;
  const int t = threadIdx.x;
  __shared__ float srow[C_];
  __shared__ __align__(16) float syt[128];
  __shared__ float wns[18];
  __shared__ float b3s;
  if (t == 0) {
    float u3v = u3[0];
    float nvs = 0.0f;
    for (int k = 0; k < 18; k++) { float vv = u3v * w3[k]; nvs += vv * vv; }
    float d = fmaxf(sqrtf(nvs), EPSF);
    float tt = 0.0f;
    for (int k = 0; k < 18; k++) tt += (u3v * w3[k] / d) * w3[k];
    float u2n = tt / fmaxf(fabsf(tt), EPSF);
    float inv3 = 1.0f / (tt * u2n);
    for (int k = 0; k < 18; k++) wns[k] = w3[k] * inv3;
    b3s = b3[0];
  }
  for (int i = t; i < C_; i += 256) srow[i] = s[b * C_ + i];
  __syncthreads();
  if (t < 128) {
    const int px = hw0 + t;
    const int h = px >> 6, w = px & 63;
    float acc = b3s;
    #pragma unroll
    for (int dh = -1; dh <= 1; dh++) {
      int hh = h + dh;
      if (hh < 0 || hh >= 64) continue;
      #pragma unroll
      for (int dw = -1; dw <= 1; dw++) {
        int ww = w + dw;
        if (ww < 0 || ww >= WID_) continue;
        int n = b * HW_ + hh * WID_ + ww;
        int k = (dh + 1) * 3 + (dw + 1);
        acc += ca[n] * wns[k] + cm[n] * wns[9 + k];
      }
    }
    syt[t] = sigmoidf(acc);
  }
  __syncthreads();
  // phase 2: stream all channels with nontemporal access (preserve x in LLC)
  const int pxs = t & 31;             // 32 slots * 4 px
  const int cg = t >> 5;              // 8 groups * 64 channels
  const f32x4 sy4 = *(const f32x4*)(&syt[pxs * 4]);
  const size_t base = (size_t)b * C_ * HW_ + hw0 + pxs * 4;
  const int c0 = cg * 64;
  #pragma unroll 8
  for (int c = c0; c < c0 + 64; c++) {
    const f32x4 u = __builtin_nontemporal_load((const f32x4*)(x + base + (size_t)c * HW_));
    const f32x4 r = u * (srow[c] * sy4);
    __builtin_nontemporal_store(r, (f32x4*)(out + base + (size_t)c * HW_));
  }
}

extern "C" void kernel_launch(void* const* d_in, const int* in_sizes, int n_in,
                              void* d_out, int out_size, void* d_ws, size_t ws_size,
                              hipStream_t stream) {
  const float* x  = (const float*)d_in[0];
  const float* w1 = (const float*)d_in[1];
  const float* b1 = (const float*)d_in[2];
  const float* u1 = (const float*)d_in[3];
  const float* w2 = (const float*)d_in[4];
  const float* b2 = (const float*)d_in[5];
  const float* u2 = (const float*)d_in[6];
  const float* w3 = (const float*)d_in[7];
  const float* b3 = (const float*)d_in[8];
  const float* u3 = (const float*)d_in[9];

  float* ws = (float*)d_ws;
  float* avg = ws;                    // 16384 floats
  float* mx  = ws + 16384;            // 16384
  float* s   = ws + 32768;            // 16384
  float* ca  = ws + 49152;            // 131072
  float* cm  = ws + 180224;           // 131072  (total ~1.2 MiB)

  pool_kernel<<<B_ * C_ / 4, 256, 0, stream>>>(x, avg, mx);
  mlp_kernel<<<dim3(4, B_), 256, 0, stream>>>(avg, mx, w1, b1, u1, w2, b2, u2, s);
  scale_pool_kernel<<<dim3(32, B_), 256, 0, stream>>>(x, s, ca, cm);
  conv_out_kernel<<<dim3(32, B_), 256, 0, stream>>>(x, s, ca, cm, w3, b3, u3, (float*)d_out);
}